// Round 12
// baseline (87.851 us; speedup 1.0000x reference)
//
#include <hip/hip_runtime.h>

// FermiLayer fused kernel set for MI355X (gfx950).
// Inputs (f32): h1(768,256) h2(768,768,64) W1n(1216,256) b1n(256)
//               W1e(1216,256) b1e(256) W2(4,64,64) b2(4,64)
// Outputs (f32, concat): h1_out(768,256), h2_out(768,768,64)
//
// Lessons encoded:
//  R6:  out2 MUST use nontemporal stores (plain stores evict h2 from L3 in
//       the graph-replay regime).
//  R7:  big prefix launches serialize; only W2T (4 blocks) must precede k_h2.
//  R8:  nt stores must be LANE-CONTIGUOUS (1 KB/instr full 128-B lines).
//  R9:  do NOT hold >1 tile in flight per block (L1/L3 thrash).
//  R10: preload hv before MFMA; col-sums from hv registers.
//  R11: wave-owns-16-rows; single EARLY lgkmcnt-only barrier.
//  R12: B-frags from pre-transposed bf16 W2T: 8 dwordx4/wave instead of 64
//       scalar gathers (TA-cycle reduction ~15 µs/CU-aggregate).

#define H1OUT_ELEMS (768 * 256)

typedef short short8 __attribute__((ext_vector_type(8)));
typedef float f32x4 __attribute__((ext_vector_type(4)));

__device__ __forceinline__ unsigned short f2bf(float f) {
    unsigned u = __builtin_bit_cast(unsigned, f);
    unsigned r = u + 0x7fffu + ((u >> 16) & 1u);
    return (unsigned short)(r >> 16);
}

// out = (hv + gelu_rescaled(x)) / sqrt(2), tanh-approx gelu.
__device__ __forceinline__ float gelu_res(float x, float hv) {
    float x2 = x * x;
    float z = x * fmaf(-0.1029432196f, x2, -2.3025850930f);
    float e = __builtin_amdgcn_exp2f(z);
    float r = __builtin_amdgcn_rcpf(1.f + e);
    return fmaf(x * r, 1.2111740f, hv * 0.70710678f);
}

// ---------------------------------------------------------------------------
// W2 transpose-convert: W2T[p][e][d] = bf16(W2[p][d][e]). grid 4, block 256.
// Must run BEFORE k_h2pre (separate tiny launch, ~2 µs).
// ---------------------------------------------------------------------------
__global__ __launch_bounds__(256) void k_w2t(
    const float* __restrict__ W2, unsigned short* __restrict__ W2T) {
    __shared__ float tile[64][65];
    const int p = blockIdx.x;
    const int t = threadIdx.x;
    #pragma unroll
    for (int i = 0; i < 16; ++i) {
        int j = i * 256 + t;
        tile[j >> 6][j & 63] = W2[p * 4096 + j];
    }
    __syncthreads();
    #pragma unroll
    for (int i = 0; i < 2; ++i) {
        int j = i * 256 + t;
        int e = j >> 3, d8 = (j & 7) * 8;
        short8 o;
        #pragma unroll
        for (int jj = 0; jj < 8; ++jj) o[jj] = (short)f2bf(tile[d8 + jj][e]);
        *reinterpret_cast<short8*>(&W2T[(size_t)(p * 64 + e) * 64 + d8]) = o;
    }
}

// ---------------------------------------------------------------------------
// Fused kernel 1:
//   blocks [0,12):    h1 per-64-row-tile column sums -> part1
//   blocks [12,316):  W1n/W1e transpose-convert -> WT bf16 (64k x 32e tiles)
//   blocks [316, +9216): h2 update; wave-local 16-row bands, one early barrier
// ---------------------------------------------------------------------------
__global__ __launch_bounds__(256) void k_h2pre(
    const float* __restrict__ h2, const unsigned short* __restrict__ W2T,
    const float* __restrict__ b2, const float* __restrict__ h1,
    const float* __restrict__ W1n, const float* __restrict__ W1e,
    float* __restrict__ out2, float* __restrict__ part2,
    float* __restrict__ part1, unsigned short* __restrict__ WT) {
    __shared__ union SM {
        struct {
            float ot[4][16][68];    // per-wave x staging    17408 B
            float red[4][4][64];    // col-sum partials       4096 B
        } g;
        float tile2[64][33];        // W transpose tile (prefix) 8448 B
    } sm;

    int b = blockIdx.x;
    const int t = threadIdx.x;

    if (b < 12) {  // ---- h1 per-64-row-tile column sums ----
        float s = 0.f;
        #pragma unroll 8
        for (int r = 0; r < 64; ++r) s += h1[(size_t)(b * 64 + r) * 256 + t];
        part1[b * 256 + t] = s;
        return;
    }
    if (b < 316) {  // ---- W transpose-convert, 64(k) x 32(e) tiles ----
        int idx = b - 12;              // 0..303
        int mtx = idx / 152;
        int r2  = idx % 152;
        int k0 = (r2 >> 3) * 64, e0 = (r2 & 7) * 32;
        const float* W = mtx ? W1e : W1n;
        #pragma unroll
        for (int i = 0; i < 8; ++i) {
            int j = i * 256 + t;
            int kr = j >> 5, ec = j & 31;
            sm.tile2[kr][ec] = W[(size_t)(k0 + kr) * 256 + e0 + ec];
        }
        __syncthreads();
        int er = t >> 3, k8 = (t & 7) * 8;
        short8 o;
        #pragma unroll
        for (int j = 0; j < 8; ++j) o[j] = (short)f2bf(sm.tile2[k8 + j][er]);
        *reinterpret_cast<short8*>(
            &WT[((size_t)mtx * 256 + e0 + er) * 1216 + k0 + k8]) = o;
        return;
    }

    // ---- h2 update: each wave owns 16 rows x 64 cols of the 64x64 tile ----
    b -= 316;
    const int ct = b % 12;
    const int n  = b / 12;
    const int m0 = ct * 64;

    const int rs = (n < 128) ? 0 : ((n < 448) ? 1 : 2);
    const int cs = (ct < 2) ? 0 : ((ct < 7) ? 1 : 2);
    int p;
    if (rs == 0)      p = (cs == 0) ? 0 : 1;
    else if (rs == 1) p = (cs == 0) ? 1 : ((cs == 1) ? 2 : 3);
    else              p = (cs == 0) ? 1 : ((cs == 1) ? 3 : 2);

    const float* src = h2 + ((size_t)n * 768 + m0) * 64;
    const int lane = t & 63;
    const int w = t >> 6;          // wave id = 16-row band
    const int lr = lane & 15, lk = lane >> 4;
    const int r0 = w * 16;

    // --- hv: wave-local linear view of rows r0..r0+15 (full-line loads) ---
    const float* hbase = src + r0 * 64;
    f32x4 hv[4];
    #pragma unroll
    for (int i = 0; i < 4; ++i)
        hv[i] = *reinterpret_cast<const f32x4*>(hbase + i * 256 + lane * 4);

    // --- A-frag loads (rows r0+lr), stay in flight across the barrier ---
    const float* arow = src + (r0 + lr) * 64 + lk * 8;
    float4 af[2][2];
    #pragma unroll
    for (int kh = 0; kh < 2; ++kh) {
        af[kh][0] = *reinterpret_cast<const float4*>(arow + kh * 32);
        af[kh][1] = *reinterpret_cast<const float4*>(arow + kh * 32 + 4);
    }

    // --- B-frags: contiguous short8 from pre-transposed W2T (L2-hot),
    //     issued before the barrier so latency hides ---
    const unsigned short* wb = W2T + (size_t)p * 4096;
    short8 bF[4][2];   // [fe][kh]
    #pragma unroll
    for (int fe = 0; fe < 4; ++fe)
        #pragma unroll
        for (int kh = 0; kh < 2; ++kh)
            bF[fe][kh] = *reinterpret_cast<const short8*>(
                wb + (fe * 16 + lr) * 64 + kh * 32 + lk * 8);

    // --- column partial sums of this wave's 16 rows (from hv regs) ---
    {
        f32x4 s;
        s[0] = hv[0][0] + hv[1][0] + hv[2][0] + hv[3][0];
        s[1] = hv[0][1] + hv[1][1] + hv[2][1] + hv[3][1];
        s[2] = hv[0][2] + hv[1][2] + hv[2][2] + hv[3][2];
        s[3] = hv[0][3] + hv[1][3] + hv[2][3] + hv[3][3];
        *reinterpret_cast<f32x4*>(&sm.g.red[w][lane >> 4][(lane & 15) * 4]) = s;
    }

    // --- the ONLY barrier: lgkmcnt-only (global loads stay in flight) ---
    asm volatile("s_waitcnt lgkmcnt(0)" ::: "memory");
    __builtin_amdgcn_s_barrier();
    asm volatile("" ::: "memory");

    // --- part2 finalize (wave 0 only; others proceed to MFMA) ---
    if (t < 64) {
        float s = 0.f;
        #pragma unroll
        for (int q = 0; q < 16; ++q) s += sm.g.red[q >> 2][q & 3][t];
        part2[((size_t)n * 12 + ct) * 64 + t] = s;
    }

    // --- convert A to bf16 fragments ---
    short8 aF[2];
    #pragma unroll
    for (int kh = 0; kh < 2; ++kh) {
        short8 o;
        o[0] = (short)f2bf(af[kh][0].x);
        o[1] = (short)f2bf(af[kh][0].y);
        o[2] = (short)f2bf(af[kh][0].z);
        o[3] = (short)f2bf(af[kh][0].w);
        o[4] = (short)f2bf(af[kh][1].x);
        o[5] = (short)f2bf(af[kh][1].y);
        o[6] = (short)f2bf(af[kh][1].z);
        o[7] = (short)f2bf(af[kh][1].w);
        aF[kh] = o;
    }

    // --- per 16-col block: 2 MFMA, stage x (wave-local)
    //     D layout: lane holds col e=fe*16+lr, rows m = r0 + lk*4 + r ---
    #pragma unroll
    for (int fe = 0; fe < 4; ++fe) {
        f32x4 acc = {};
        acc = __builtin_amdgcn_mfma_f32_16x16x32_bf16(aF[0], bF[fe][0], acc, 0, 0, 0);
        acc = __builtin_amdgcn_mfma_f32_16x16x32_bf16(aF[1], bF[fe][1], acc, 0, 0, 0);
        float bias = b2[p * 64 + fe * 16 + lr];
        #pragma unroll
        for (int r = 0; r < 4; ++r)
            sm.g.ot[w][lk * 4 + r][fe * 16 + lr] = acc[r] + bias;
    }

    // --- wave-local epilogue: LDS transpose-read + gelu + full-line nt store
    //     (compiler inserts lgkmcnt for the same-wave ot dependency) ---
    float* dst = out2 + ((size_t)n * 768 + m0 + r0) * 64;
    #pragma unroll
    for (int i = 0; i < 4; ++i) {
        int row = i * 4 + (lane >> 4), col = (lane & 15) * 4;
        f32x4 x4 = *reinterpret_cast<const f32x4*>(&sm.g.ot[w][row][col]);
        f32x4 o;
        o[0] = gelu_res(x4[0], hv[i][0]);
        o[1] = gelu_res(x4[1], hv[i][1]);
        o[2] = gelu_res(x4[2], hv[i][2]);
        o[3] = gelu_res(x4[3], hv[i][3]);
        __builtin_nontemporal_store(
            o, reinterpret_cast<f32x4*>(dst + i * 256 + lane * 4));
    }
}

// ---------------------------------------------------------------------------
// Fused kernel 2: build feats rows (16) in LDS, then GEMM vs WT + epilogue.
// grid (48, 2), block 256 (4 waves; each wave 32 output cols). Swapped MFMA.
// ---------------------------------------------------------------------------
__global__ __launch_bounds__(256) void k_h1f(
    const float* __restrict__ h1, const unsigned short* __restrict__ WT,
    const float* __restrict__ part2, const float* __restrict__ part1,
    const float* __restrict__ b1n, const float* __restrict__ b1e,
    float* __restrict__ out1) {
    __shared__ unsigned short FL[16][1224];

    const int n0 = blockIdx.x * 16;
    const int half = blockIdx.y;
    const int t = threadIdx.x;
    const bool dn = (n0 >= 448);
    const bool nucl = (n0 < 128);

    // phase 1: h1 slice (cols 0..255)
    #pragma unroll
    for (int i = 0; i < 16; ++i) {
        int idx = i * 256 + t;
        int r = idx >> 8, c = idx & 255;
        FL[r][c] = f2bf(h1[(size_t)(n0 + r) * 256 + c]);
    }
    // phase 2: h2_mean (cols 256..447)
    #pragma unroll
    for (int i = 0; i < 12; ++i) {
        int idx = i * 256 + t;
        int r = idx / 192, c = idx % 192;
        int sec = c >> 6, d = c & 63;
        int s2 = (dn && sec >= 1) ? (3 - sec) : sec;
        const float* pr = part2 + (size_t)(n0 + r) * 768;
        float s;
        if (s2 == 0) {
            s = (pr[d] + pr[64 + d]) * (1.f / 128.f);
        } else {
            int q0 = (s2 == 1) ? 2 : 7;
            s = 0.f;
            #pragma unroll
            for (int q = 0; q < 5; ++q) s += pr[(q0 + q) * 64 + d];
            s *= (1.f / 320.f);
        }
        FL[r][256 + c] = f2bf(s);
    }
    // phase 3: h1_mean (cols 448..1215), shared across the 16 rows
    #pragma unroll
    for (int i = 0; i < 3; ++i) {
        int j = i * 256 + t;
        int sec = j >> 8, e2 = j & 255;
        int s2 = (dn && sec >= 1) ? (3 - sec) : sec;
        float s;
        if (s2 == 0) {
            s = (part1[e2] + part1[256 + e2]) * (1.f / 128.f);
        } else {
            int q0 = (s2 == 1) ? 2 : 7;
            s = 0.f;
            #pragma unroll
            for (int q = 0; q < 5; ++q) s += part1[(q0 + q) * 256 + e2];
            s *= (1.f / 320.f);
        }
        unsigned short bv = f2bf(s);
        #pragma unroll
        for (int r = 0; r < 16; ++r) FL[r][448 + j] = bv;
    }
    __syncthreads();

    const int w = t >> 6, lane = t & 63;
    const int lr = lane & 15, lk = lane >> 4;
    const int e0 = half * 128 + w * 32;
    const unsigned short* BT = WT + (nucl ? 0 : (size_t)256 * 1216);
    const unsigned short* br0 = BT + (size_t)(e0 + lr) * 1216 + lk * 8;
    const unsigned short* br1 = br0 + (size_t)16 * 1216;
    const unsigned short* ar = &FL[lr][lk * 8];

    f32x4 acc0 = {}, acc1 = {};
    #pragma unroll 2
    for (int k = 0; k < 1216; k += 32) {
        short8 aF = *reinterpret_cast<const short8*>(ar + k);
        short8 b0 = *reinterpret_cast<const short8*>(br0 + k);
        short8 b1 = *reinterpret_cast<const short8*>(br1 + k);
        acc0 = __builtin_amdgcn_mfma_f32_16x16x32_bf16(b0, aF, acc0, 0, 0, 0);
        acc1 = __builtin_amdgcn_mfma_f32_16x16x32_bf16(b1, aF, acc1, 0, 0, 0);
    }

    const float* bb = nucl ? b1n : b1e;
    const int m = n0 + lr;
    #pragma unroll
    for (int j = 0; j < 2; ++j) {
        const f32x4 a = j ? acc1 : acc0;
        int e = e0 + j * 16 + lk * 4;
        f32x4 bias4 = *reinterpret_cast<const f32x4*>(bb + e);
        f32x4 hv = *reinterpret_cast<const f32x4*>(h1 + (size_t)m * 256 + e);
        f32x4 o;
        o[0] = gelu_res(a[0] + bias4[0], hv[0]);
        o[1] = gelu_res(a[1] + bias4[1], hv[1]);
        o[2] = gelu_res(a[2] + bias4[2], hv[2]);
        o[3] = gelu_res(a[3] + bias4[3], hv[3]);
        *reinterpret_cast<f32x4*>(out1 + (size_t)m * 256 + e) = o;
    }
}

// ---------------------------------------------------------------------------
extern "C" void kernel_launch(void* const* d_in, const int* in_sizes, int n_in,
                              void* d_out, int out_size, void* d_ws, size_t ws_size,
                              hipStream_t stream) {
    const float* h1  = (const float*)d_in[0];
    const float* h2  = (const float*)d_in[1];
    const float* W1n = (const float*)d_in[2];
    const float* b1n = (const float*)d_in[3];
    const float* W1e = (const float*)d_in[4];
    const float* b1e = (const float*)d_in[5];
    const float* W2  = (const float*)d_in[6];
    const float* b2  = (const float*)d_in[7];

    float* out1 = (float*)d_out;             // h1_out: 768*256
    float* out2 = out1 + H1OUT_ELEMS;        // h2_out: 768*768*64

    float* part2 = (float*)d_ws;                                  // 768*12*64 f32
    float* part1 = part2 + 768 * 12 * 64;                         // 12*256 f32
    unsigned short* WT  = (unsigned short*)(part1 + 12 * 256);    // 2*256*1216 bf16
    unsigned short* W2T = WT + (size_t)2 * 256 * 1216;            // 4*64*64 bf16

    k_w2t<<<4, 256, 0, stream>>>(W2, W2T);
    k_h2pre<<<dim3(316 + 12 * 768), 256, 0, stream>>>(
        h2, W2T, b2, h1, W1n, W1e, out2, part2, part1, WT);
    k_h1f<<<dim3(48, 2), 256, 0, stream>>>(h1, WT, part2, part1, b1n, b1e, out1);
}

// Round 13
// 73.110 us; speedup vs baseline: 1.2016x; 1.2016x over previous
//
#include <hip/hip_runtime.h>

// FermiLayer fused kernel set for MI355X (gfx950).
// Inputs (f32): h1(768,256) h2(768,768,64) W1n(1216,256) b1n(256)
//               W1e(1216,256) b1e(256) W2(4,64,64) b2(4,64)
// Outputs (f32, concat): h1_out(768,256), h2_out(768,768,64)
//
// Lessons encoded:
//  R6:  out2 MUST use nontemporal stores (plain stores evict h2 from L3 in
//       the graph-replay regime).
//  R7/R12: ANY launch before the big h2 kernel costs 10-14 µs timed
//       (pipeline/L3-warmth break). h2 kernel launches FIRST. Always.
//  R8:  nt stores must be LANE-CONTIGUOUS (1 KB/instr full 128-B lines).
//  R9:  do NOT hold >1 tile in flight per block (L1/L3 thrash).
//  R10: preload hv before MFMA; col-sums from hv registers.
//  R11: wave-owns-16-rows; lgkmcnt-only barriers.
//  R13: per-block W2T in LDS (aliased with ot staging): vectorized bF
//       (8x ds_read_b128) with no pre-launch.

#define H1OUT_ELEMS (768 * 256)

typedef short short8 __attribute__((ext_vector_type(8)));
typedef float f32x4 __attribute__((ext_vector_type(4)));

__device__ __forceinline__ unsigned short f2bf(float f) {
    unsigned u = __builtin_bit_cast(unsigned, f);
    unsigned r = u + 0x7fffu + ((u >> 16) & 1u);
    return (unsigned short)(r >> 16);
}

// out = (hv + gelu_rescaled(x)) / sqrt(2), tanh-approx gelu.
__device__ __forceinline__ float gelu_res(float x, float hv) {
    float x2 = x * x;
    float z = x * fmaf(-0.1029432196f, x2, -2.3025850930f);
    float e = __builtin_amdgcn_exp2f(z);
    float r = __builtin_amdgcn_rcpf(1.f + e);
    return fmaf(x * r, 1.2111740f, hv * 0.70710678f);
}

// ---------------------------------------------------------------------------
// Fused kernel 1:
//   blocks [0,12):    h1 per-64-row-tile column sums -> part1
//   blocks [12,316):  W1n/W1e transpose-convert -> WT bf16 (64k x 32e tiles)
//   blocks [316, +9216): h2 update; wave-local 16-row bands; in-LDS W2T
// ---------------------------------------------------------------------------
__global__ __launch_bounds__(256) void k_h2pre(
    const float* __restrict__ h2, const float* __restrict__ W2,
    const float* __restrict__ b2, const float* __restrict__ h1,
    const float* __restrict__ W1n, const float* __restrict__ W1e,
    float* __restrict__ out2, float* __restrict__ part2,
    float* __restrict__ part1, unsigned short* __restrict__ WT) {
    __shared__ union SM {
        float ot[4][16][68];        // x staging (phase 2)       17408 B
        unsigned short BT[64][72];  // W2T bf16 (phases 0-1)      9216 B
        float tile2[64][33];        // W transpose tile (prefix)  8448 B
    } sm;
    __shared__ float red[4][4][64]; // col-sum partials           4096 B

    int b = blockIdx.x;
    const int t = threadIdx.x;

    if (b < 12) {  // ---- h1 per-64-row-tile column sums ----
        float s = 0.f;
        #pragma unroll 8
        for (int r = 0; r < 64; ++r) s += h1[(size_t)(b * 64 + r) * 256 + t];
        part1[b * 256 + t] = s;
        return;
    }
    if (b < 316) {  // ---- W transpose-convert, 64(k) x 32(e) tiles ----
        int idx = b - 12;              // 0..303
        int mtx = idx / 152;
        int r2  = idx % 152;
        int k0 = (r2 >> 3) * 64, e0 = (r2 & 7) * 32;
        const float* W = mtx ? W1e : W1n;
        #pragma unroll
        for (int i = 0; i < 8; ++i) {
            int j = i * 256 + t;
            int kr = j >> 5, ec = j & 31;
            sm.tile2[kr][ec] = W[(size_t)(k0 + kr) * 256 + e0 + ec];
        }
        __syncthreads();
        int er = t >> 3, k8 = (t & 7) * 8;
        short8 o;
        #pragma unroll
        for (int j = 0; j < 8; ++j) o[j] = (short)f2bf(sm.tile2[k8 + j][er]);
        *reinterpret_cast<short8*>(
            &WT[((size_t)mtx * 256 + e0 + er) * 1216 + k0 + k8]) = o;
        return;
    }

    // ---- h2 update: each wave owns 16 rows x 64 cols of the 64x64 tile ----
    b -= 316;
    const int ct = b % 12;
    const int n  = b / 12;
    const int m0 = ct * 64;

    const int rs = (n < 128) ? 0 : ((n < 448) ? 1 : 2);
    const int cs = (ct < 2) ? 0 : ((ct < 7) ? 1 : 2);
    int p;
    if (rs == 0)      p = (cs == 0) ? 0 : 1;
    else if (rs == 1) p = (cs == 0) ? 1 : ((cs == 1) ? 2 : 3);
    else              p = (cs == 0) ? 1 : ((cs == 1) ? 3 : 2);

    const float* src = h2 + ((size_t)n * 768 + m0) * 64;
    const int lane = t & 63;
    const int w = t >> 6;          // wave id = 16-row band
    const int lr = lane & 15, lk = lane >> 4;
    const int r0 = w * 16;

    // --- W2 stripe loads FIRST (lane = d-row, wave = 16-e stripe) ---
    // thread t: d = lane, e0w = w*16; loads W2[p][d][e0w..e0w+15]
    const float* wrow = W2 + p * 4096 + lane * 64 + w * 16;
    float4 wv4[4];
    #pragma unroll
    for (int i = 0; i < 4; ++i)
        wv4[i] = *reinterpret_cast<const float4*>(wrow + i * 4);

    // --- hv: wave-local linear view of rows r0..r0+15 (full-line loads) ---
    const float* hbase = src + r0 * 64;
    f32x4 hv[4];
    #pragma unroll
    for (int i = 0; i < 4; ++i)
        hv[i] = *reinterpret_cast<const f32x4*>(hbase + i * 256 + lane * 4);

    // --- A-frag loads LAST (stay in flight longest) ---
    const float* arow = src + (r0 + lr) * 64 + lk * 8;
    float4 af[2][2];
    #pragma unroll
    for (int kh = 0; kh < 2; ++kh) {
        af[kh][0] = *reinterpret_cast<const float4*>(arow + kh * 32);
        af[kh][1] = *reinterpret_cast<const float4*>(arow + kh * 32 + 4);
    }

    // --- phase 0: write BT[e][d] = bf16(W2[p][d][e]) (2-way banks = free) ---
    #pragma unroll
    for (int i = 0; i < 4; ++i) {
        unsigned short v0 = f2bf(wv4[i].x);
        unsigned short v1 = f2bf(wv4[i].y);
        unsigned short v2 = f2bf(wv4[i].z);
        unsigned short v3 = f2bf(wv4[i].w);
        sm.BT[w * 16 + i * 4 + 0][lane] = v0;
        sm.BT[w * 16 + i * 4 + 1][lane] = v1;
        sm.BT[w * 16 + i * 4 + 2][lane] = v2;
        sm.BT[w * 16 + i * 4 + 3][lane] = v3;
    }

    // --- column partial sums of this wave's 16 rows (from hv regs) ---
    {
        f32x4 s;
        s[0] = hv[0][0] + hv[1][0] + hv[2][0] + hv[3][0];
        s[1] = hv[0][1] + hv[1][1] + hv[2][1] + hv[3][1];
        s[2] = hv[0][2] + hv[1][2] + hv[2][2] + hv[3][2];
        s[3] = hv[0][3] + hv[1][3] + hv[2][3] + hv[3][3];
        *reinterpret_cast<f32x4*>(&red[w][lane >> 4][(lane & 15) * 4]) = s;
    }

    // --- barrier 1: lgkmcnt-only (af global loads stay in flight) ---
    asm volatile("s_waitcnt lgkmcnt(0)" ::: "memory");
    __builtin_amdgcn_s_barrier();
    asm volatile("" ::: "memory");

    // --- part2 finalize (wave 0 only) ---
    if (t < 64) {
        float s = 0.f;
        #pragma unroll
        for (int q = 0; q < 16; ++q) s += red[q >> 2][q & 3][t];
        part2[((size_t)n * 12 + ct) * 64 + t] = s;
    }

    // --- phase 1: vectorized bF reads (identical across waves; 16B each) ---
    short8 bF[4][2];   // [fe][kh]
    #pragma unroll
    for (int fe = 0; fe < 4; ++fe)
        #pragma unroll
        for (int kh = 0; kh < 2; ++kh)
            bF[fe][kh] = *reinterpret_cast<const short8*>(
                &sm.BT[fe * 16 + lr][kh * 32 + lk * 8]);

    // --- convert A to bf16 fragments ---
    short8 aF[2];
    #pragma unroll
    for (int kh = 0; kh < 2; ++kh) {
        short8 o;
        o[0] = (short)f2bf(af[kh][0].x);
        o[1] = (short)f2bf(af[kh][0].y);
        o[2] = (short)f2bf(af[kh][0].z);
        o[3] = (short)f2bf(af[kh][0].w);
        o[4] = (short)f2bf(af[kh][1].x);
        o[5] = (short)f2bf(af[kh][1].y);
        o[6] = (short)f2bf(af[kh][1].z);
        o[7] = (short)f2bf(af[kh][1].w);
        aF[kh] = o;
    }

    // --- barrier 2: all bF reads done before ot overwrites BT ---
    asm volatile("s_waitcnt lgkmcnt(0)" ::: "memory");
    __builtin_amdgcn_s_barrier();
    asm volatile("" ::: "memory");

    // --- phase 2: MFMA + wave-local x staging
    //     D layout: lane holds col e=fe*16+lr, rows m = r0 + lk*4 + r ---
    #pragma unroll
    for (int fe = 0; fe < 4; ++fe) {
        f32x4 acc = {};
        acc = __builtin_amdgcn_mfma_f32_16x16x32_bf16(aF[0], bF[fe][0], acc, 0, 0, 0);
        acc = __builtin_amdgcn_mfma_f32_16x16x32_bf16(aF[1], bF[fe][1], acc, 0, 0, 0);
        float bias = b2[p * 64 + fe * 16 + lr];
        #pragma unroll
        for (int r = 0; r < 4; ++r)
            sm.ot[w][lk * 4 + r][fe * 16 + lr] = acc[r] + bias;
    }

    // --- wave-local epilogue: LDS transpose-read + gelu + full-line nt store
    //     (compiler inserts lgkmcnt for the same-wave ot dependency) ---
    float* dst = out2 + ((size_t)n * 768 + m0 + r0) * 64;
    #pragma unroll
    for (int i = 0; i < 4; ++i) {
        int row = i * 4 + (lane >> 4), col = (lane & 15) * 4;
        f32x4 x4 = *reinterpret_cast<const f32x4*>(&sm.ot[w][row][col]);
        f32x4 o;
        o[0] = gelu_res(x4[0], hv[i][0]);
        o[1] = gelu_res(x4[1], hv[i][1]);
        o[2] = gelu_res(x4[2], hv[i][2]);
        o[3] = gelu_res(x4[3], hv[i][3]);
        __builtin_nontemporal_store(
            o, reinterpret_cast<f32x4*>(dst + i * 256 + lane * 4));
    }
}

// ---------------------------------------------------------------------------
// Fused kernel 2: build feats rows (16) in LDS, then GEMM vs WT + epilogue.
// grid (48, 2), block 256 (4 waves; each wave 32 output cols). Swapped MFMA.
// ---------------------------------------------------------------------------
__global__ __launch_bounds__(256) void k_h1f(
    const float* __restrict__ h1, const unsigned short* __restrict__ WT,
    const float* __restrict__ part2, const float* __restrict__ part1,
    const float* __restrict__ b1n, const float* __restrict__ b1e,
    float* __restrict__ out1) {
    __shared__ unsigned short FL[16][1224];

    const int n0 = blockIdx.x * 16;
    const int half = blockIdx.y;
    const int t = threadIdx.x;
    const bool dn = (n0 >= 448);
    const bool nucl = (n0 < 128);

    // phase 1: h1 slice (cols 0..255)
    #pragma unroll
    for (int i = 0; i < 16; ++i) {
        int idx = i * 256 + t;
        int r = idx >> 8, c = idx & 255;
        FL[r][c] = f2bf(h1[(size_t)(n0 + r) * 256 + c]);
    }
    // phase 2: h2_mean (cols 256..447)
    #pragma unroll
    for (int i = 0; i < 12; ++i) {
        int idx = i * 256 + t;
        int r = idx / 192, c = idx % 192;
        int sec = c >> 6, d = c & 63;
        int s2 = (dn && sec >= 1) ? (3 - sec) : sec;
        const float* pr = part2 + (size_t)(n0 + r) * 768;
        float s;
        if (s2 == 0) {
            s = (pr[d] + pr[64 + d]) * (1.f / 128.f);
        } else {
            int q0 = (s2 == 1) ? 2 : 7;
            s = 0.f;
            #pragma unroll
            for (int q = 0; q < 5; ++q) s += pr[(q0 + q) * 64 + d];
            s *= (1.f / 320.f);
        }
        FL[r][256 + c] = f2bf(s);
    }
    // phase 3: h1_mean (cols 448..1215), shared across the 16 rows
    #pragma unroll
    for (int i = 0; i < 3; ++i) {
        int j = i * 256 + t;
        int sec = j >> 8, e2 = j & 255;
        int s2 = (dn && sec >= 1) ? (3 - sec) : sec;
        float s;
        if (s2 == 0) {
            s = (part1[e2] + part1[256 + e2]) * (1.f / 128.f);
        } else {
            int q0 = (s2 == 1) ? 2 : 7;
            s = 0.f;
            #pragma unroll
            for (int q = 0; q < 5; ++q) s += part1[(q0 + q) * 256 + e2];
            s *= (1.f / 320.f);
        }
        unsigned short bv = f2bf(s);
        #pragma unroll
        for (int r = 0; r < 16; ++r) FL[r][448 + j] = bv;
    }
    __syncthreads();

    const int w = t >> 6, lane = t & 63;
    const int lr = lane & 15, lk = lane >> 4;
    const int e0 = half * 128 + w * 32;
    const unsigned short* BT = WT + (nucl ? 0 : (size_t)256 * 1216);
    const unsigned short* br0 = BT + (size_t)(e0 + lr) * 1216 + lk * 8;
    const unsigned short* br1 = br0 + (size_t)16 * 1216;
    const unsigned short* ar = &FL[lr][lk * 8];

    f32x4 acc0 = {}, acc1 = {};
    #pragma unroll 2
    for (int k = 0; k < 1216; k += 32) {
        short8 aF = *reinterpret_cast<const short8*>(ar + k);
        short8 b0 = *reinterpret_cast<const short8*>(br0 + k);
        short8 b1 = *reinterpret_cast<const short8*>(br1 + k);
        acc0 = __builtin_amdgcn_mfma_f32_16x16x32_bf16(b0, aF, acc0, 0, 0, 0);
        acc1 = __builtin_amdgcn_mfma_f32_16x16x32_bf16(b1, aF, acc1, 0, 0, 0);
    }

    const float* bb = nucl ? b1n : b1e;
    const int m = n0 + lr;
    #pragma unroll
    for (int j = 0; j < 2; ++j) {
        const f32x4 a = j ? acc1 : acc0;
        int e = e0 + j * 16 + lk * 4;
        f32x4 bias4 = *reinterpret_cast<const f32x4*>(bb + e);
        f32x4 hv = *reinterpret_cast<const f32x4*>(h1 + (size_t)m * 256 + e);
        f32x4 o;
        o[0] = gelu_res(a[0] + bias4[0], hv[0]);
        o[1] = gelu_res(a[1] + bias4[1], hv[1]);
        o[2] = gelu_res(a[2] + bias4[2], hv[2]);
        o[3] = gelu_res(a[3] + bias4[3], hv[3]);
        *reinterpret_cast<f32x4*>(out1 + (size_t)m * 256 + e) = o;
    }
}

// ---------------------------------------------------------------------------
extern "C" void kernel_launch(void* const* d_in, const int* in_sizes, int n_in,
                              void* d_out, int out_size, void* d_ws, size_t ws_size,
                              hipStream_t stream) {
    const float* h1  = (const float*)d_in[0];
    const float* h2  = (const float*)d_in[1];
    const float* W1n = (const float*)d_in[2];
    const float* b1n = (const float*)d_in[3];
    const float* W1e = (const float*)d_in[4];
    const float* b1e = (const float*)d_in[5];
    const float* W2  = (const float*)d_in[6];
    const float* b2  = (const float*)d_in[7];

    float* out1 = (float*)d_out;             // h1_out: 768*256
    float* out2 = out1 + H1OUT_ELEMS;        // h2_out: 768*768*64

    float* part2 = (float*)d_ws;                                  // 768*12*64 f32
    float* part1 = part2 + 768 * 12 * 64;                         // 12*256 f32
    unsigned short* WT = (unsigned short*)(part1 + 12 * 256);     // 2*256*1216 bf16

    k_h2pre<<<dim3(316 + 12 * 768), 256, 0, stream>>>(
        h2, W2, b2, h1, W1n, W1e, out2, part2, part1, WT);
    k_h1f<<<dim3(48, 2), 256, 0, stream>>>(h1, WT, part2, part1, b1n, b1e, out1);
}